// Round 1
// baseline (284.291 us; speedup 1.0000x reference)
//
#include <hip/hip_runtime.h>
#include <math.h>

#define BB 512       // batch rows (M)
#define DD 512       // depth (K)
#define CC 100000    // classes (N)
#define MARGIN2 0.5f
#define PI_F 3.14159265358979323846f

#define BM 128
#define BN 160
#define BK 64
#define KSTEPS (DD / BK)   // 8

typedef __bf16 bf16x8 __attribute__((ext_vector_type(8)));
typedef float f32x4 __attribute__((ext_vector_type(4)));

static __device__ __forceinline__ unsigned short f2bf(float f) {
    union { float f; unsigned u; } v; v.f = f;
    unsigned r = v.u + 0x7FFFu + ((v.u >> 16) & 1u);   // round-to-nearest-even
    return (unsigned short)(r >> 16);
}

// swizzled LDS byte offset for row-major [row][64 x bf16] tiles (row stride 128B)
static __device__ __forceinline__ int swz(int row, int kbyte) {
    return row * 128 + (kbyte ^ ((row & 7) << 4));
}

// ---------------- K1: row-normalize x -> bf16 ----------------
__global__ __launch_bounds__(256) void k_norm_x(const float* __restrict__ x,
                                                unsigned short* __restrict__ xnb) {
    const int lane = threadIdx.x & 63;
    const int row  = blockIdx.x * 4 + (threadIdx.x >> 6);
    const float* xr = x + (size_t)row * DD;
    float4 v0 = *(const float4*)(xr + lane * 4);
    float4 v1 = *(const float4*)(xr + lane * 4 + 256);
    float s = v0.x*v0.x + v0.y*v0.y + v0.z*v0.z + v0.w*v0.w
            + v1.x*v1.x + v1.y*v1.y + v1.z*v1.z + v1.w*v1.w;
    #pragma unroll
    for (int m = 32; m; m >>= 1) s += __shfl_xor(s, m, 64);
    float rs = rsqrtf(fmaxf(s, 1e-12f));
    ushort4 o0, o1;
    o0.x = f2bf(v0.x * rs); o0.y = f2bf(v0.y * rs);
    o0.z = f2bf(v0.z * rs); o0.w = f2bf(v0.w * rs);
    o1.x = f2bf(v1.x * rs); o1.y = f2bf(v1.y * rs);
    o1.z = f2bf(v1.z * rs); o1.w = f2bf(v1.w * rs);
    *(ushort4*)(xnb + (size_t)row * DD + lane * 4)       = o0;
    *(ushort4*)(xnb + (size_t)row * DD + lane * 4 + 256) = o1;
}

// ---------------- K2: column rnorm of W ----------------
__global__ __launch_bounds__(256) void k_norm_w(const float* __restrict__ W,
                                                float* __restrict__ rnorm) {
    const int c = blockIdx.x * 256 + threadIdx.x;
    if (c >= CC) return;
    const float* p = W + c;
    float s = 0.f;
    #pragma unroll 16
    for (int d = 0; d < DD; ++d) {
        float v = p[(size_t)d * CC];
        s += v * v;
    }
    rnorm[c] = rsqrtf(fmaxf(s, 1e-12f));
}

// ---------------- K3: bf16 MFMA GEMM with fused epilogue scale ----------------
__global__ __launch_bounds__(512) void k_gemm(const unsigned short* __restrict__ xnb,
                                              const float* __restrict__ W,
                                              const float* __restrict__ rnorm,
                                              float* __restrict__ out) {
    __shared__ __align__(16) unsigned char Ash[BM * BK * 2];  // [m][k] bf16, swizzled
    __shared__ __align__(16) unsigned char Bsh[BN * BK * 2];  // [n][k] bf16, swizzled

    const int tid = threadIdx.x;
    const int bid = blockIdx.x;
    const int mb = bid & 3;        // 4 M blocks, inner -> consecutive blocks share W panel
    const int nb = bid >> 2;       // 625 N blocks
    const int M0 = mb * BM;
    const int N0 = nb * BN;

    // ---- A staging: 2 slots of 16B per thread (128x64 bf16 tile = 1024 slots) ----
    int a_goff[2], a_lds[2];
    #pragma unroll
    for (int i = 0; i < 2; ++i) {
        int s = tid + i * 512;
        int row = s >> 3;          // 0..127
        int c8  = s & 7;           // 8 chunks of 8 bf16 per row
        a_goff[i] = (M0 + row) * DD + c8 * 8;
        a_lds[i]  = swz(row, c8 * 16);
    }

    // ---- B staging: 5 column-quad tasks per thread (160 n x 16 kq = 2560 tasks) ----
    int b_goff[5], b_lds[5];
    #pragma unroll
    for (int i = 0; i < 5; ++i) {
        int s = tid + i * 512;
        int n  = s % BN;           // consecutive tid -> consecutive n (coalesced)
        int kq = s / BN;           // 0..15
        b_goff[i] = (kq * 4) * CC + N0 + n;
        b_lds[i]  = n * 128 + ((kq * 8) ^ ((n & 7) << 4));
    }

    int4  areg[2];
    float breg[5][4];

    // prologue: prefetch tile t=0 into registers
    #pragma unroll
    for (int i = 0; i < 2; ++i)
        areg[i] = *(const int4*)(xnb + a_goff[i]);
    #pragma unroll
    for (int i = 0; i < 5; ++i) {
        const float* p = W + b_goff[i];
        breg[i][0] = p[0];
        breg[i][1] = p[CC];
        breg[i][2] = p[2 * CC];
        breg[i][3] = p[3 * CC];
    }

    const int lane = tid & 63;
    const int wid  = tid >> 6;
    const int wm = wid >> 1;       // 0..3 -> 32 rows each
    const int wn = wid & 1;        // 0..1 -> 80 cols each
    const int lr = lane & 15;
    const int lg = lane >> 4;

    f32x4 acc[2][5];
    #pragma unroll
    for (int mf = 0; mf < 2; ++mf)
        #pragma unroll
        for (int nf = 0; nf < 5; ++nf)
            acc[mf][nf] = (f32x4)0.f;

    for (int t = 0; t < KSTEPS; ++t) {
        __syncthreads();           // previous iteration done reading LDS
        // store staged tile to LDS
        #pragma unroll
        for (int i = 0; i < 2; ++i)
            *(int4*)(Ash + a_lds[i]) = areg[i];
        #pragma unroll
        for (int i = 0; i < 5; ++i) {
            uint2 w;
            w.x = (unsigned)f2bf(breg[i][0]) | ((unsigned)f2bf(breg[i][1]) << 16);
            w.y = (unsigned)f2bf(breg[i][2]) | ((unsigned)f2bf(breg[i][3]) << 16);
            *(uint2*)(Bsh + b_lds[i]) = w;
        }
        __syncthreads();           // tile visible to all waves

        // prefetch next tile into registers (overlaps with MFMA below)
        if (t + 1 < KSTEPS) {
            #pragma unroll
            for (int i = 0; i < 2; ++i)
                areg[i] = *(const int4*)(xnb + a_goff[i] + (t + 1) * BK);
            #pragma unroll
            for (int i = 0; i < 5; ++i) {
                const float* p = W + b_goff[i] + (t + 1) * (BK * CC);
                breg[i][0] = p[0];
                breg[i][1] = p[CC];
                breg[i][2] = p[2 * CC];
                breg[i][3] = p[3 * CC];
            }
        }

        // compute: 2 k-substeps of 32, 2x5 fragments
        #pragma unroll
        for (int ks = 0; ks < 2; ++ks) {
            bf16x8 af[2], bfr[5];
            #pragma unroll
            for (int mf = 0; mf < 2; ++mf)
                af[mf] = *(const bf16x8*)(Ash + swz(wm * 32 + mf * 16 + lr, ks * 64 + lg * 16));
            #pragma unroll
            for (int nf = 0; nf < 5; ++nf)
                bfr[nf] = *(const bf16x8*)(Bsh + swz(wn * 80 + nf * 16 + lr, ks * 64 + lg * 16));
            #pragma unroll
            for (int mf = 0; mf < 2; ++mf)
                #pragma unroll
                for (int nf = 0; nf < 5; ++nf)
                    acc[mf][nf] = __builtin_amdgcn_mfma_f32_16x16x32_bf16(
                        af[mf], bfr[nf], acc[mf][nf], 0, 0, 0);
        }
    }

    // epilogue: scale by column rnorm, store fp32
    #pragma unroll
    for (int nf = 0; nf < 5; ++nf) {
        const int colg = N0 + wn * 80 + nf * 16 + lr;
        const float rn = rnorm[colg];
        #pragma unroll
        for (int mf = 0; mf < 2; ++mf) {
            const int rowg = M0 + wm * 32 + mf * 16 + lg * 4;
            #pragma unroll
            for (int r = 0; r < 4; ++r)
                out[(size_t)(rowg + r) * CC + colg] = acc[mf][nf][r] * rn;
        }
    }
}

// ---------------- K4: margin fixup at label positions ----------------
__global__ __launch_bounds__(512) void k_fix(const int* __restrict__ lab,
                                             float* __restrict__ out) {
    const int b = threadIdx.x;
    const int c = lab[b];
    const size_t idx = (size_t)b * CC + c;
    float t = out[idx];
    t = fminf(fmaxf(t, -1.f), 1.f);
    float th = acosf(t) + MARGIN2;
    th = fminf(th, PI_F);              // min(t, t + (pi - stopgrad(t))) value-wise
    out[idx] = cosf(th);               // M3 == 0: no additive term
}

extern "C" void kernel_launch(void* const* d_in, const int* in_sizes, int n_in,
                              void* d_out, int out_size, void* d_ws, size_t ws_size,
                              hipStream_t stream) {
    const float* x   = (const float*)d_in[0];
    const float* W   = (const float*)d_in[1];
    const int*   lab = (const int*)d_in[2];
    float* out = (float*)d_out;

    unsigned short* xnb = (unsigned short*)d_ws;                    // 512*512*2 = 512 KB
    float* rnorm = (float*)((char*)d_ws + (size_t)BB * DD * 2);     // 100000*4 = 400 KB

    k_norm_x<<<dim3(BB / 4), dim3(256), 0, stream>>>(x, xnb);
    k_norm_w<<<dim3((CC + 255) / 256), dim3(256), 0, stream>>>(W, rnorm);
    k_gemm<<<dim3((BB / BM) * (CC / BN)), dim3(512), 0, stream>>>(xnb, W, rnorm, out);
    k_fix<<<dim3(1), dim3(512), 0, stream>>>(lab, out);
}

// Round 2
// 249.413 us; speedup vs baseline: 1.1398x; 1.1398x over previous
//
#include <hip/hip_runtime.h>
#include <math.h>

#define BB 512       // batch rows (M)
#define DD 512       // depth (K)
#define CC 100000    // classes (N)
#define MARGIN2 0.5f
#define PI_F 3.14159265358979323846f

#define BM 128
#define BN 160
#define BK 64
#define KSTEPS (DD / BK)   // 8

typedef __bf16 bf16x8 __attribute__((ext_vector_type(8)));
typedef float f32x4 __attribute__((ext_vector_type(4)));

static __device__ __forceinline__ unsigned short f2bf(float f) {
    union { float f; unsigned u; } v; v.f = f;
    unsigned r = v.u + 0x7FFFu + ((v.u >> 16) & 1u);   // round-to-nearest-even
    return (unsigned short)(r >> 16);
}

// swizzled LDS byte offset for row-major [row][64 x bf16] tiles (row stride 128B)
static __device__ __forceinline__ int swz(int row, int kbyte) {
    return row * 128 + (kbyte ^ ((row & 7) << 4));
}

// ---------------- K1: row-normalize x -> bf16 ----------------
__global__ __launch_bounds__(256) void k_norm_x(const float* __restrict__ x,
                                                unsigned short* __restrict__ xnb) {
    const int lane = threadIdx.x & 63;
    const int row  = blockIdx.x * 4 + (threadIdx.x >> 6);
    const float* xr = x + (size_t)row * DD;
    float4 v0 = *(const float4*)(xr + lane * 4);
    float4 v1 = *(const float4*)(xr + lane * 4 + 256);
    float s = v0.x*v0.x + v0.y*v0.y + v0.z*v0.z + v0.w*v0.w
            + v1.x*v1.x + v1.y*v1.y + v1.z*v1.z + v1.w*v1.w;
    #pragma unroll
    for (int m = 32; m; m >>= 1) s += __shfl_xor(s, m, 64);
    float rs = rsqrtf(fmaxf(s, 1e-12f));
    ushort4 o0, o1;
    o0.x = f2bf(v0.x * rs); o0.y = f2bf(v0.y * rs);
    o0.z = f2bf(v0.z * rs); o0.w = f2bf(v0.w * rs);
    o1.x = f2bf(v1.x * rs); o1.y = f2bf(v1.y * rs);
    o1.z = f2bf(v1.z * rs); o1.w = f2bf(v1.w * rs);
    *(ushort4*)(xnb + (size_t)row * DD + lane * 4)       = o0;
    *(ushort4*)(xnb + (size_t)row * DD + lane * 4 + 256) = o1;
}

// ---------------- K2: bf16 MFMA GEMM, fused column-norm + epilogue scale ----------------
__global__ __launch_bounds__(512) void k_gemm(const unsigned short* __restrict__ xnb,
                                              const float* __restrict__ W,
                                              float* __restrict__ out) {
    __shared__ __align__(16) unsigned char Ash[BM * BK * 2];  // 16 KB, [m][k] bf16 swizzled
    __shared__ __align__(16) unsigned char Bsh[BN * BK * 2];  // 20 KB, [n][k] bf16 swizzled
    // after the K loop: Bsh reused as float part[16][160], Ash reused as float rn[160]

    const int tid = threadIdx.x;
    const int bid = blockIdx.x;

    // bijective XCD swizzle: hw assigns block b -> XCD b%8; give each XCD a
    // contiguous v-range so the 4 mb-blocks of a panel share one XCD's L2.
    // 2500 blocks = 8*312 + 4 -> XCDs 0..3 get 313, XCDs 4..7 get 312.
    const int xcd = bid & 7;
    const int jj  = bid >> 3;
    const int v   = (xcd < 4) ? (xcd * 313 + jj) : (1252 + (xcd - 4) * 312 + jj);
    const int mb  = v & 3;         // 4 M blocks share a W panel, consecutive on same XCD
    const int nb  = v >> 2;        // 625 N panels
    const int M0 = mb * BM;
    const int N0 = nb * BN;

    // ---- A staging: 2 slots of 16B per thread (128x64 bf16 tile = 1024 slots) ----
    int a_goff[2], a_lds[2];
    #pragma unroll
    for (int i = 0; i < 2; ++i) {
        int s = tid + i * 512;
        int row = s >> 3;
        int c8  = s & 7;
        a_goff[i] = (M0 + row) * DD + c8 * 8;
        a_lds[i]  = swz(row, c8 * 16);
    }

    // ---- B staging: 5 column-quad tasks per thread; s = kq*160 + n (bijective) ----
    int b_goff[5], b_lds[5], b_n[5];
    #pragma unroll
    for (int i = 0; i < 5; ++i) {
        int s = tid + i * 512;
        int n  = s % BN;
        int kq = s / BN;
        b_n[i]    = s;                 // == kq*160 + n, the part[] slot
        b_goff[i] = (kq * 4) * CC + N0 + n;
        b_lds[i]  = n * 128 + ((kq * 8) ^ ((n & 7) << 4));
    }

    int4  areg[2];
    float breg[5][4];
    float bsq[5] = {0.f, 0.f, 0.f, 0.f, 0.f};   // running column sumsq partials

    // prologue: prefetch tile t=0 into registers
    #pragma unroll
    for (int i = 0; i < 2; ++i)
        areg[i] = *(const int4*)(xnb + a_goff[i]);
    #pragma unroll
    for (int i = 0; i < 5; ++i) {
        const float* p = W + b_goff[i];
        breg[i][0] = p[0];
        breg[i][1] = p[CC];
        breg[i][2] = p[2 * CC];
        breg[i][3] = p[3 * CC];
    }

    const int lane = tid & 63;
    const int wid  = tid >> 6;
    const int wm = wid >> 1;       // 0..3 -> 32 rows each
    const int wn = wid & 1;        // 0..1 -> 80 cols each
    const int lr = lane & 15;
    const int lg = lane >> 4;

    f32x4 acc[2][5];
    #pragma unroll
    for (int mf = 0; mf < 2; ++mf)
        #pragma unroll
        for (int nf = 0; nf < 5; ++nf)
            acc[mf][nf] = (f32x4)0.f;

    for (int t = 0; t < KSTEPS; ++t) {
        __syncthreads();           // previous iteration done reading LDS
        #pragma unroll
        for (int i = 0; i < 2; ++i)
            *(int4*)(Ash + a_lds[i]) = areg[i];
        #pragma unroll
        for (int i = 0; i < 5; ++i) {
            bsq[i] += breg[i][0] * breg[i][0] + breg[i][1] * breg[i][1]
                    + breg[i][2] * breg[i][2] + breg[i][3] * breg[i][3];
            uint2 w;
            w.x = (unsigned)f2bf(breg[i][0]) | ((unsigned)f2bf(breg[i][1]) << 16);
            w.y = (unsigned)f2bf(breg[i][2]) | ((unsigned)f2bf(breg[i][3]) << 16);
            *(uint2*)(Bsh + b_lds[i]) = w;
        }
        __syncthreads();           // tile visible to all waves

        // prefetch next tile into registers (overlaps with MFMA below)
        if (t + 1 < KSTEPS) {
            #pragma unroll
            for (int i = 0; i < 2; ++i)
                areg[i] = *(const int4*)(xnb + a_goff[i] + (t + 1) * BK);
            #pragma unroll
            for (int i = 0; i < 5; ++i) {
                const float* p = W + b_goff[i] + (t + 1) * (BK * CC);
                breg[i][0] = p[0];
                breg[i][1] = p[CC];
                breg[i][2] = p[2 * CC];
                breg[i][3] = p[3 * CC];
            }
        }

        // compute: 2 k-substeps of 32, 2x5 fragments.
        // OPERANDS SWAPPED: D = B^T * A^T = (A*B)^T  ->  col(lane&15)=m-row,
        // reg index r = consecutive n  ->  float4-contiguous epilogue stores.
        #pragma unroll
        for (int ks = 0; ks < 2; ++ks) {
            bf16x8 af[2], bfr[5];
            #pragma unroll
            for (int mf = 0; mf < 2; ++mf)
                af[mf] = *(const bf16x8*)(Ash + swz(wm * 32 + mf * 16 + lr, ks * 64 + lg * 16));
            #pragma unroll
            for (int nf = 0; nf < 5; ++nf)
                bfr[nf] = *(const bf16x8*)(Bsh + swz(wn * 80 + nf * 16 + lr, ks * 64 + lg * 16));
            #pragma unroll
            for (int mf = 0; mf < 2; ++mf)
                #pragma unroll
                for (int nf = 0; nf < 5; ++nf)
                    acc[mf][nf] = __builtin_amdgcn_mfma_f32_16x16x32_bf16(
                        bfr[nf], af[mf], acc[mf][nf], 0, 0, 0);
        }
    }

    // ---- deterministic column-norm reduction in LDS (reuse Bsh/Ash) ----
    __syncthreads();                       // all waves done with Ash/Bsh reads
    float* part = (float*)Bsh;             // [16][160] = 10240 B <= 20480 B
    #pragma unroll
    for (int i = 0; i < 5; ++i)
        part[b_n[i]] = bsq[i];             // slot s = kq*160+n, unique owner
    __syncthreads();
    float* rn = (float*)Ash;               // [160] floats
    if (tid < BN) {
        float s = 0.f;
        #pragma unroll
        for (int k = 0; k < 16; ++k)
            s += part[k * BN + tid];       // fixed order -> deterministic
        rn[tid] = rsqrtf(fmaxf(s, 1e-12f));
    }
    __syncthreads();

    // ---- epilogue: scale by column rnorm, contiguous float4 stores ----
    #pragma unroll
    for (int nf = 0; nf < 5; ++nf) {
        const int nloc = wn * 80 + nf * 16 + lg * 4;
        const f32x4 rn4 = *(const f32x4*)(rn + nloc);
        #pragma unroll
        for (int mf = 0; mf < 2; ++mf) {
            const size_t base = (size_t)(M0 + wm * 32 + mf * 16 + lr) * CC + N0 + nloc;
            f32x4 o;
            #pragma unroll
            for (int r = 0; r < 4; ++r)
                o[r] = acc[mf][nf][r] * rn4[r];
            *(f32x4*)(out + base) = o;
        }
    }
}

// ---------------- K3: margin fixup at label positions ----------------
__global__ __launch_bounds__(512) void k_fix(const int* __restrict__ lab,
                                             float* __restrict__ out) {
    const int b = threadIdx.x;
    const int c = lab[b];
    const size_t idx = (size_t)b * CC + c;
    float t = out[idx];
    t = fminf(fmaxf(t, -1.f), 1.f);
    float th = acosf(t) + MARGIN2;
    th = fminf(th, PI_F);              // min(t, t + (pi - stopgrad(t))) value-wise
    out[idx] = cosf(th);               // M3 == 0: no additive term
}

extern "C" void kernel_launch(void* const* d_in, const int* in_sizes, int n_in,
                              void* d_out, int out_size, void* d_ws, size_t ws_size,
                              hipStream_t stream) {
    const float* x   = (const float*)d_in[0];
    const float* W   = (const float*)d_in[1];
    const int*   lab = (const int*)d_in[2];
    float* out = (float*)d_out;

    unsigned short* xnb = (unsigned short*)d_ws;   // 512*512*2 = 512 KB scratch

    k_norm_x<<<dim3(BB / 4), dim3(256), 0, stream>>>(x, xnb);
    k_gemm<<<dim3((BB / BM) * (CC / BN)), dim3(512), 0, stream>>>(xnb, W, out);
    k_fix<<<dim3(1), dim3(512), 0, stream>>>(lab, out);
}